// Round 14
// baseline (299.770 us; speedup 1.0000x reference)
//
#include <hip/hip_runtime.h>

#define N_NODES  50000
#define N_EDGES  800000
#define HID      128
#define OUT_C    16
#define N_GRAPHS 128
#define MAXDEG   64     // Poisson(16): P(deg>=64) ~ 1e-19/node — clamped anyway
#define NSLICE   6250   // N_NODES / 8; slice s owns [s*6250,(s+1)*6250)
#define EPB      8192   // edges per fill chunk
#define FILLB    784    // 98 chunks x 8 slices
#define GEMMB    782    // ceil(50000/64)
#define PREPW    64     // W2-transpose blocks: 64*256 = 16384 = HID*HID
#define AGB      3125   // 50000 / 16 exactly
#define PAD      136    // +8 bf16 pad -> frag reads 2-way (free) not 16-way

typedef __attribute__((ext_vector_type(8))) short bf16x8;
typedef __attribute__((ext_vector_type(4))) float f32x4;
typedef __attribute__((ext_vector_type(8))) unsigned short us8;
typedef __attribute__((ext_vector_type(4))) unsigned short us4;

__device__ __forceinline__ unsigned short f2bf(float f) {
  unsigned u = __float_as_uint(f);
  u += 0x7fffu + ((u >> 16) & 1u);   // RNE
  return (unsigned short)(u >> 16);
}

// ---------------- shared MFMA compute+store, 256-thread version -------------
// 16x16x32 MFMA; A: m=lane&15,k=quad*8+j (LDS); B: n=lane&15,k=quad*8+j
// loaded straight from global fp32 W[k][n] (L2-broadcast). 64KB W-read per
// block x 782 blocks = 50 MB — fine; gemm1 hides under fill anyway.
// C/D: col=lane&15,row=quad*4+reg.
__device__ __forceinline__ void gemm_compute_store(
    unsigned short* sA, const float* __restrict__ W,
    unsigned short* __restrict__ T, int base) {
  const int tid = threadIdx.x;
  const int lane = tid & 63;
  const int w = tid >> 6;
  const int l15 = lane & 15;
  const int quad = lane >> 4;
  __syncthreads();

  f32x4 acc[4][2];
#pragma unroll
  for (int nt = 0; nt < 4; ++nt)
#pragma unroll
    for (int c = 0; c < 2; ++c) acc[nt][c] = (f32x4)(0.f);

  const int ct0 = w * 2;
  const int ncol = ct0 * 16 + l15;
#pragma unroll
  for (int ks = 0; ks < 4; ++ks) {
    const int koff = ks * 32 + quad * 8;
    bf16x8 a[4], bfr[2];
#pragma unroll
    for (int c = 0; c < 2; ++c) {
      const float* wp = W + (size_t)koff * HID + ncol + c * 16;
#pragma unroll
      for (int j = 0; j < 8; ++j) bfr[c][j] = (short)f2bf(wp[(size_t)j * HID]);
    }
#pragma unroll
    for (int nt = 0; nt < 4; ++nt)
      a[nt] = *(const bf16x8*)(sA + (nt * 16 + l15) * PAD + koff);
#pragma unroll
    for (int nt = 0; nt < 4; ++nt)
#pragma unroll
      for (int c = 0; c < 2; ++c)
        acc[nt][c] = __builtin_amdgcn_mfma_f32_16x16x32_bf16(a[nt], bfr[c], acc[nt][c], 0, 0, 0);
  }
  __syncthreads();

#pragma unroll
  for (int nt = 0; nt < 4; ++nt)
#pragma unroll
    for (int c = 0; c < 2; ++c)
#pragma unroll
      for (int r = 0; r < 4; ++r)
        sA[(nt * 16 + quad * 4 + r) * PAD + (ct0 + c) * 16 + l15] = f2bf(acc[nt][c][r]);
  __syncthreads();
#pragma unroll
  for (int i = 0; i < 4; ++i) {
    int idx = tid + i * 256;
    int nrow = idx >> 4;
    int col = (idx & 15) * 8;
    int node = base + nrow;
    if (node < N_NODES)
      *(us8*)(T + (size_t)node * HID + col) = *(const us8*)(sA + nrow * PAD + col);
  }
}

// stage A from fp32 (convert to bf16): 64 rows x 32 float4 = 2048
__device__ __forceinline__ void stage_a_f32(unsigned short* sA,
                                            const float* __restrict__ H, int base) {
#pragma unroll
  for (int i = 0; i < 8; ++i) {
    int idx = threadIdx.x + i * 256;
    int nrow = idx >> 5;
    int c4 = (idx & 31) * 4;
    float4 v = make_float4(0.f, 0.f, 0.f, 0.f);
    int node = base + nrow;
    if (node < N_NODES) v = *(const float4*)(H + (size_t)node * HID + c4);
    us4 b;
    b.x = f2bf(v.x); b.y = f2bf(v.y); b.z = f2bf(v.z); b.w = f2bf(v.w);
    *(us4*)(sA + nrow * PAD + c4) = b;
  }
}

// ---- mega: fill (0..783) | bounds (784) | gemm1 (785..1566) | W2-prep ------
// fill is scattered-traffic-bound (~55-58us, rounds 4/5/6/9/10) — gemm1 +
// W2-prep (independent of fill) hide under it. All branches LDS-light.
__global__ __launch_bounds__(256) void mega_kernel(
    const int* __restrict__ src, const int* __restrict__ dst,
    int* __restrict__ deg, unsigned short* __restrict__ ell,
    const int* __restrict__ batch, int* __restrict__ start,
    const float* __restrict__ x, const float* __restrict__ W1,
    unsigned short* __restrict__ T,
    const float* __restrict__ W2, unsigned short* __restrict__ wt2) {
  __shared__ unsigned short sA[64 * PAD];   // 17.4 KB
  int b = blockIdx.x;
  if (b < FILLB) {
    const int slice = b & 7;
    const int e0 = (b >> 3) * EPB;
    const int e1 = min(e0 + EPB, N_EDGES);
    const unsigned lo = slice * NSLICE;
    for (int e = e0 + threadIdx.x; e < e1; e += 256) {
      int d = __builtin_nontemporal_load(dst + e);
      if ((unsigned)(d - lo) < (unsigned)NSLICE) {
        int p = atomicAdd(&deg[d], 1);
        if (p < MAXDEG) ell[(d << 6) + p] = (unsigned short)src[e];
      }
    }
  } else if (b == FILLB) {
    int t = threadIdx.x;                       // graph bounds (batch sorted)
    if (t <= N_GRAPHS) {
      int lo = 0, hi = N_NODES;
      while (lo < hi) {
        int mid = (lo + hi) >> 1;
        if (batch[mid] < t) lo = mid + 1; else hi = mid;
      }
      start[t] = lo;
    }
  } else if (b < FILLB + 1 + GEMMB) {
    const int base = (b - FILLB - 1) * 64;
    stage_a_f32(sA, x, base);
    gemm_compute_store(sA, W1, T, base);
  } else {
    // W2 transpose + bf16: wt2[n][k] = f2bf(W2[k][n]) (single us8 B-frag load)
    int idx = (b - FILLB - 1 - GEMMB) * 256 + threadIdx.x;   // 0..16383
    int k = idx >> 7, n = idx & 127;
    wt2[n * HID + k] = f2bf(W2[k * HID + n]);
  }
}

// ---------------- wide-gather aggregation core ------------------------------
// Round-13 lesson: aggregation is gather-LATENCY-bound (VALUBusy ~18%,
// request rate low). Old layout: lane=2ch, one 256B row per instruction,
// 8 edges in flight. New: lane=8ch (us8), the 4 lane-quads fetch 4 DIFFERENT
// rows per instruction (1KB/instr) -> 32 edges in flight at the same unroll.
// ell/deg loads are quad-uniform (broadcast-coalesced); no cross-lane ops in
// the hot loop; 2-step shfl_xor butterfly merges quad-partials at the end.
// Output: acc[8] = relu(agg + bias) for channels (lane&15)*8..+8, all lanes.
__device__ __forceinline__ void agg_node8(
    int node, int lane, const us8* __restrict__ T8,
    const unsigned short* __restrict__ ell, const int* __restrict__ deg,
    const float* __restrict__ bias, float* acc) {
  const int l15 = lane & 15;
  const int quad = lane >> 4;
  int dn = deg[node];
  float dd = rsqrtf((float)dn + 1.0f);
  int m = min(dn, MAXDEG);
  // self-loop: quad 0 initializes with dd^2 * own row
  if (quad == 0) {
    us8 sv = T8[(size_t)node * 16 + l15];
    float ws = dd * dd;
#pragma unroll
    for (int c = 0; c < 8; ++c)
      acc[c] = ws * __int_as_float((unsigned)sv[c] << 16);
  } else {
#pragma unroll
    for (int c = 0; c < 8; ++c) acc[c] = 0.f;
  }
  int mr = (m + 3) >> 2;               // 4-edge groups; quad handles edge 4g+quad
  for (int jg = 0; jg < mr; jg += 8) {
    int lim = min(8, mr - jg);
    int s[8];
#pragma unroll
    for (int q = 0; q < 8; ++q)
      if (q < lim) {
        int e = (jg + q) * 4 + quad;   // quad-uniform address: broadcast load
        s[q] = (e < m) ? (int)ell[(node << 6) + e] : -1;
      }
    us8 t[8]; float w[8];
#pragma unroll
    for (int q = 0; q < 8; ++q)
      if (q < lim) {
        int sq = (s[q] < 0) ? 0 : s[q];
        t[q] = T8[(size_t)sq * 16 + l15];              // 4 rows / instruction
        w[q] = (s[q] < 0) ? 0.f : rsqrtf((float)deg[sq] + 1.0f) * dd;
      }
#pragma unroll
    for (int q = 0; q < 8; ++q)
      if (q < lim)
#pragma unroll
        for (int c = 0; c < 8; ++c)
          acc[c] += w[q] * __int_as_float((unsigned)t[q][c] << 16);
  }
  // merge the 4 quad-partitions (butterfly: every lane ends with the total)
#pragma unroll
  for (int c = 0; c < 8; ++c) {
    acc[c] += __shfl_xor(acc[c], 16);
    acc[c] += __shfl_xor(acc[c], 32);
  }
  const float4 b0 = *(const float4*)(bias + l15 * 8);
  const float4 b1 = *(const float4*)(bias + l15 * 8 + 4);
  acc[0] = fmaxf(acc[0] + b0.x, 0.f);
  acc[1] = fmaxf(acc[1] + b0.y, 0.f);
  acc[2] = fmaxf(acc[2] + b0.z, 0.f);
  acc[3] = fmaxf(acc[3] + b0.w, 0.f);
  acc[4] = fmaxf(acc[4] + b1.x, 0.f);
  acc[5] = fmaxf(acc[5] + b1.y, 0.f);
  acc[6] = fmaxf(acc[6] + b1.z, 0.f);
  acc[7] = fmaxf(acc[7] + b1.w, 0.f);
}

// ---------------- fused agg1 + gemm2, one node per wave ---------------------
// 3125 blocks x 16 waves = 50000 waves (full agg TLP); B from bf16 wt2.
__global__ __launch_bounds__(1024) void agg_gemm_kernel(
    const us8* __restrict__ T8, const unsigned short* __restrict__ ell,
    const int* __restrict__ deg, const float* __restrict__ bias,
    const unsigned short* __restrict__ wt2, unsigned short* __restrict__ T2) {
  __shared__ unsigned short sA[16 * PAD];   // 4.4 KB
  const int tid = threadIdx.x;
  const int lane = tid & 63;
  const int w = tid >> 6;            // 0..15 — one node per wave
  const int l15 = lane & 15;
  const int quad = lane >> 4;
  const int base = blockIdx.x * 16;  // 3125 * 16 = 50000 exactly

  {
    float acc[8];
    agg_node8(base + w, lane, T8, ell, deg, bias, acc);
    if (quad == 0) {
      us8 o;
#pragma unroll
      for (int c = 0; c < 8; ++c) o[c] = f2bf(acc[c]);
      *(us8*)(sA + w * PAD + l15 * 8) = o;   // 16 lanes x 16B contiguous
    }
  }
  __syncthreads();

  f32x4 acc = (f32x4)(0.f);
  if (w < 8) {                       // wave w owns col-tile w (cols w*16..+16)
    const unsigned short* wrow = wt2 + (size_t)(w * 16 + l15) * HID;
#pragma unroll
    for (int ks = 0; ks < 4; ++ks) {
      const int koff = ks * 32 + quad * 8;
      bf16x8 a = *(const bf16x8*)(sA + l15 * PAD + koff);
      bf16x8 bfr = *(const bf16x8*)(wrow + koff);
      acc = __builtin_amdgcn_mfma_f32_16x16x32_bf16(a, bfr, acc, 0, 0, 0);
    }
  }
  __syncthreads();                   // uniform barrier (no sync inside the if)
  if (w < 8) {
#pragma unroll
    for (int r = 0; r < 4; ++r)
      sA[(quad * 4 + r) * PAD + w * 16 + l15] = f2bf(acc[r]);
  }
  __syncthreads();
  if (tid < 256) {                   // 16 rows x 16 us8 chunks = 256
    int nrow = tid >> 4;
    int col = (tid & 15) * 8;
    *(us8*)(T2 + (size_t)(base + nrow) * HID + col) = *(const us8*)(sA + nrow * PAD + col);
  }
}

// ---------------- agg2: aggregation + bias + relu -> bf16 H (for pooling) ---
__global__ __launch_bounds__(256) void aggregate_kernel(
    const us8* __restrict__ T8, const unsigned short* __restrict__ ell,
    const int* __restrict__ deg, const float* __restrict__ bias,
    unsigned short* __restrict__ Hb) {
  int node = (blockIdx.x * blockDim.x + threadIdx.x) >> 6;
  int lane = threadIdx.x & 63;
  if (node >= N_NODES) return;
  float acc[8];
  agg_node8(node, lane, T8, ell, deg, bias, acc);
  if ((lane >> 4) == 0) {
    us8 o;
#pragma unroll
    for (int c = 0; c < 8; ++c) o[c] = f2bf(acc[c]);
    *(us8*)(Hb + (size_t)node * HID + (lane & 15) * 8) = o;
  }
}

// ---------------- pool partial sums: 4 blocks per graph -> fp32 atomics -----
__global__ __launch_bounds__(256) void pool_partial_kernel(
    const unsigned int* __restrict__ Hb, const int* __restrict__ start,
    float* __restrict__ pooled) {
  __shared__ float2 red[4][64];
  int g = blockIdx.x >> 2;
  int chunk = blockIdx.x & 3;
  int n0 = start[g], n1 = start[g + 1];
  int lane = threadIdx.x & 63, w = threadIdx.x >> 6;
  float ax = 0.f, ay = 0.f;
  for (int n = n0 + chunk * 4 + w; n < n1; n += 16) {
    unsigned h = Hb[(size_t)n * 64 + lane];
    ax += __int_as_float(h << 16);
    ay += __int_as_float(h & 0xffff0000u);
  }
  red[w][lane] = make_float2(ax, ay);
  __syncthreads();
  if (threadIdx.x < 64) {
    float2 a = red[0][lane], b = red[1][lane], c = red[2][lane], d = red[3][lane];
    atomicAdd(&pooled[g * HID + lane * 2],     a.x + b.x + c.x + d.x);
    atomicAdd(&pooled[g * HID + lane * 2 + 1], a.y + b.y + c.y + d.y);
  }
}

// ---------------- FC head + log_softmax on pooled sums (1 wave / graph) -----
__global__ __launch_bounds__(64) void head_kernel(
    const float* __restrict__ pooled, const int* __restrict__ start,
    const float* __restrict__ Wfc, const float* __restrict__ bfc,
    float* __restrict__ out) {
  int g = blockIdx.x;
  int lane = threadIdx.x;
  int o = lane & 15;
  float inv = 1.0f / fmaxf((float)(start[g + 1] - start[g]), 1.0f);
  float part = 0.f;
  for (int k = (lane >> 4); k < HID; k += 4)
    part += pooled[g * HID + k] * inv * Wfc[k * OUT_C + o];
  part += __shfl_xor(part, 16);
  part += __shfl_xor(part, 32);
  float logit = part + bfc[o];
  float m = logit;
#pragma unroll
  for (int d = 8; d >= 1; d >>= 1) m = fmaxf(m, __shfl_xor(m, d, 16));
  float e = __expf(logit - m);
  float s = e;
#pragma unroll
  for (int d = 8; d >= 1; d >>= 1) s += __shfl_xor(s, d, 16);
  float r = logit - m - __logf(s);
  if (lane < 16) out[g * OUT_C + o] = r;
}

extern "C" void kernel_launch(void* const* d_in, const int* in_sizes, int n_in,
                              void* d_out, int out_size, void* d_ws, size_t ws_size,
                              hipStream_t stream) {
  const float* x    = (const float*)d_in[0];
  const int*   ei   = (const int*)d_in[1];
  const int*   batch= (const int*)d_in[2];
  const float* W1   = (const float*)d_in[3];
  const float* b1   = (const float*)d_in[4];
  const float* W2   = (const float*)d_in[5];
  const float* b2   = (const float*)d_in[6];
  const float* Wfc  = (const float*)d_in[7];
  const float* bfc  = (const float*)d_in[8];
  float* out = (float*)d_out;
  const int* src = ei;              // edge_index[0]
  const int* dst = ei + N_EDGES;    // edge_index[1]

  char* p = (char*)d_ws;
  auto alloc = [&](size_t bytes) { char* r = p; p += (bytes + 255) & ~255ull; return r; };
  int*   degI   = (int*)alloc((size_t)N_NODES * 4);
  int*   start  = (int*)alloc((N_GRAPHS + 1) * 4);
  float* pooled = (float*)alloc((size_t)N_GRAPHS * HID * 4);
  unsigned short* wt2 = (unsigned short*)alloc((size_t)HID * HID * 2);
  unsigned short* ell = (unsigned short*)alloc((size_t)N_NODES * MAXDEG * 2); // 6.4 MB
  unsigned short* T   = (unsigned short*)alloc((size_t)N_NODES * HID * 2);    // 12.8 MB
  unsigned short* T2  = (unsigned short*)alloc((size_t)N_NODES * HID * 2);    // 12.8 MB
  unsigned short* Hb  = (unsigned short*)alloc((size_t)N_NODES * HID * 2);    // 12.8 MB

  hipMemsetAsync(degI, 0, (size_t)N_NODES * 4, stream);
  hipMemsetAsync(pooled, 0, (size_t)N_GRAPHS * HID * 4, stream);

  int agg_blocks = (N_NODES * 64 + 255) / 256;

  mega_kernel<<<FILLB + 1 + GEMMB + PREPW, 256, 0, stream>>>(
      src, dst, degI, ell, batch, start, x, W1, T, W2, wt2);
  agg_gemm_kernel<<<AGB, 1024, 0, stream>>>((const us8*)T, ell, degI,
                                            b1, wt2, T2);
  aggregate_kernel<<<agg_blocks, 256, 0, stream>>>((const us8*)T2, ell, degI, b2, Hb);
  pool_partial_kernel<<<N_GRAPHS * 4, 256, 0, stream>>>((const unsigned int*)Hb, start,
                                                        pooled);
  head_kernel<<<N_GRAPHS, 64, 0, stream>>>(pooled, start, Wfc, bfc, out);
}

// Round 15
// 239.632 us; speedup vs baseline: 1.2510x; 1.2510x over previous
//
#include <hip/hip_runtime.h>

#define N_NODES  50000
#define N_EDGES  800000
#define HID      128
#define OUT_C    16
#define N_GRAPHS 128
#define MAXDEG   64     // Poisson(16): P(deg>=64) ~ 1e-19/node — clamped anyway
#define NSLICE   6250   // N_NODES / 8; slice s owns [s*6250,(s+1)*6250)
#define EPB      4096   // edges per fill chunk (r15: halved -> 2x fill blocks)
#define FILLB    1568   // 196 chunks x 8 slices
#define GEMMB    782    // ceil(50000/64)
#define AGB      3125   // 50000 / 16 exactly
#define PAD      136    // +8 bf16 pad -> frag reads 2-way (free) not 16-way

typedef __attribute__((ext_vector_type(8))) short bf16x8;
typedef __attribute__((ext_vector_type(4))) float f32x4;
typedef __attribute__((ext_vector_type(8))) unsigned short us8;
typedef __attribute__((ext_vector_type(4))) unsigned short us4;

__device__ __forceinline__ unsigned short f2bf(float f) {
  unsigned u = __float_as_uint(f);
  u += 0x7fffu + ((u >> 16) & 1u);   // RNE
  return (unsigned short)(u >> 16);
}

// ---------------- shared MFMA compute+store, 256-thread version -------------
// 16x16x32 MFMA; A: m=lane&15,k=quad*8+j (LDS); B: n=lane&15,k=quad*8+j
// loaded straight from global fp32 W[k][n] (L2-broadcast, no LDS, no
// transpose-conflicts). C/D: col=lane&15,row=quad*4+reg.
__device__ __forceinline__ void gemm_compute_store(
    unsigned short* sA, const float* __restrict__ W,
    unsigned short* __restrict__ T, int base) {
  const int tid = threadIdx.x;
  const int lane = tid & 63;
  const int w = tid >> 6;
  const int l15 = lane & 15;
  const int quad = lane >> 4;
  __syncthreads();

  f32x4 acc[4][2];
#pragma unroll
  for (int nt = 0; nt < 4; ++nt)
#pragma unroll
    for (int c = 0; c < 2; ++c) acc[nt][c] = (f32x4)(0.f);

  const int ct0 = w * 2;
  const int ncol = ct0 * 16 + l15;
#pragma unroll
  for (int ks = 0; ks < 4; ++ks) {
    const int koff = ks * 32 + quad * 8;
    bf16x8 a[4], bfr[2];
#pragma unroll
    for (int c = 0; c < 2; ++c) {
      const float* wp = W + (size_t)koff * HID + ncol + c * 16;
#pragma unroll
      for (int j = 0; j < 8; ++j) bfr[c][j] = (short)f2bf(wp[(size_t)j * HID]);
    }
#pragma unroll
    for (int nt = 0; nt < 4; ++nt)
      a[nt] = *(const bf16x8*)(sA + (nt * 16 + l15) * PAD + koff);
#pragma unroll
    for (int nt = 0; nt < 4; ++nt)
#pragma unroll
      for (int c = 0; c < 2; ++c)
        acc[nt][c] = __builtin_amdgcn_mfma_f32_16x16x32_bf16(a[nt], bfr[c], acc[nt][c], 0, 0, 0);
  }
  __syncthreads();

#pragma unroll
  for (int nt = 0; nt < 4; ++nt)
#pragma unroll
    for (int c = 0; c < 2; ++c)
#pragma unroll
      for (int r = 0; r < 4; ++r)
        sA[(nt * 16 + quad * 4 + r) * PAD + (ct0 + c) * 16 + l15] = f2bf(acc[nt][c][r]);
  __syncthreads();
#pragma unroll
  for (int i = 0; i < 4; ++i) {
    int idx = tid + i * 256;
    int nrow = idx >> 4;
    int col = (idx & 15) * 8;
    int node = base + nrow;
    if (node < N_NODES)
      *(us8*)(T + (size_t)node * HID + col) = *(const us8*)(sA + nrow * PAD + col);
  }
}

// stage A from fp32 (convert to bf16): 64 rows x 32 float4 = 2048
__device__ __forceinline__ void stage_a_f32(unsigned short* sA,
                                            const float* __restrict__ H, int base) {
#pragma unroll
  for (int i = 0; i < 8; ++i) {
    int idx = threadIdx.x + i * 256;
    int nrow = idx >> 5;
    int c4 = (idx & 31) * 4;
    float4 v = make_float4(0.f, 0.f, 0.f, 0.f);
    int node = base + nrow;
    if (node < N_NODES) v = *(const float4*)(H + (size_t)node * HID + c4);
    us4 b;
    b.x = f2bf(v.x); b.y = f2bf(v.y); b.z = f2bf(v.z); b.w = f2bf(v.w);
    *(us4*)(sA + nrow * PAD + c4) = b;
  }
}

// ---- mega: fill (0..1567) | bounds (1568) | gemm1 (1569..2350) -------------
// fill is scattered-write/atomic-bound (~55-58us, rounds 4/5/6/9/10) — gemm1
// (independent of fill) hides under it. All branches LDS-light (17.4 KB).
// r15: 2x fill blocks probe whether more waves hide scatter latency.
__global__ __launch_bounds__(256) void mega_kernel(
    const int* __restrict__ src, const int* __restrict__ dst,
    int* __restrict__ deg, unsigned short* __restrict__ ell,
    const int* __restrict__ batch, int* __restrict__ start,
    const float* __restrict__ x, const float* __restrict__ W1,
    unsigned short* __restrict__ T) {
  __shared__ unsigned short sA[64 * PAD];   // 17.4 KB
  int b = blockIdx.x;
  if (b < FILLB) {
    const int slice = b & 7;
    const int e0 = (b >> 3) * EPB;
    const int e1 = min(e0 + EPB, N_EDGES);
    const unsigned lo = slice * NSLICE;
    for (int e = e0 + threadIdx.x; e < e1; e += 256) {
      int d = __builtin_nontemporal_load(dst + e);
      if ((unsigned)(d - lo) < (unsigned)NSLICE) {
        int p = atomicAdd(&deg[d], 1);
        if (p < MAXDEG) ell[(d << 6) + p] = (unsigned short)src[e];
      }
    }
  } else if (b == FILLB) {
    int t = threadIdx.x;                       // graph bounds (batch sorted)
    if (t <= N_GRAPHS) {
      int lo = 0, hi = N_NODES;
      while (lo < hi) {
        int mid = (lo + hi) >> 1;
        if (batch[mid] < t) lo = mid + 1; else hi = mid;
      }
      start[t] = lo;
    }
  } else {
    const int base = (b - FILLB - 1) * 64;
    stage_a_f32(sA, x, base);
    gemm_compute_store(sA, W1, T, base);
  }
}

// ---------------- per-lane aggregation core (round-12 formulation) ----------
// lane owns 2 bf16 channels; coalesced ell load + parallel deg gather, then
// readlane-broadcast with 8 independent row gathers in flight. Measured best
// of three cores (r2-MLP < THIS < r14-wide: VALU+request-rate costs invert).
__device__ __forceinline__ void agg_node(
    int node, int lane, const unsigned int* __restrict__ Tb,
    const unsigned short* __restrict__ ell, const int* __restrict__ deg,
    float bx, float by, float& ox, float& oy) {
  int dn = deg[node];
  float dd = rsqrtf((float)dn + 1.0f);
  unsigned sv = Tb[(size_t)node * 64 + lane];
  float wself = dd * dd;
  float ax = __int_as_float(sv << 16) * wself;
  float ay = __int_as_float(sv & 0xffff0000u) * wself;
  int m = min(dn, MAXDEG);
  int s0 = node << 6;
  int sidx = 0; float wv = 0.f;
  if (lane < m) {
    sidx = (int)ell[s0 + lane];       // coalesced (ELL row contiguous)
    wv = rsqrtf((float)deg[sidx] + 1.0f) * dd;   // parallel gather
  }
  int j = 0;
  for (; j + 8 <= m; j += 8) {
#pragma unroll
    for (int q = 0; q < 8; ++q) {     // 8 independent row gathers in flight
      int s = __builtin_amdgcn_readlane(sidx, j + q);
      float w = __int_as_float(__builtin_amdgcn_readlane(__float_as_int(wv), j + q));
      unsigned t = Tb[(size_t)s * 64 + lane];
      ax += w * __int_as_float(t << 16);
      ay += w * __int_as_float(t & 0xffff0000u);
    }
  }
  for (; j < m; ++j) {
    int s = __builtin_amdgcn_readlane(sidx, j);
    float w = __int_as_float(__builtin_amdgcn_readlane(__float_as_int(wv), j));
    unsigned t = Tb[(size_t)s * 64 + lane];
    ax += w * __int_as_float(t << 16);
    ay += w * __int_as_float(t & 0xffff0000u);
  }
  ox = fmaxf(ax + bx, 0.f);
  oy = fmaxf(ay + by, 0.f);
}

// ---------------- fused agg1 + gemm2, one node per wave ---------------------
// 3125 blocks x 16 waves = 50000 waves (full agg TLP), 16-row MFMA tile on
// W2 (8 active waves, 1 col-tile each, B direct from global fp32).
__global__ __launch_bounds__(1024) void agg_gemm_kernel(
    const unsigned int* __restrict__ Tb, const unsigned short* __restrict__ ell,
    const int* __restrict__ deg, const float* __restrict__ bias,
    const float* __restrict__ W, unsigned short* __restrict__ T2) {
  __shared__ unsigned short sA[16 * PAD];   // 4.4 KB
  const int tid = threadIdx.x;
  const int lane = tid & 63;
  const int w = tid >> 6;            // 0..15 — one node per wave
  const int l15 = lane & 15;
  const int quad = lane >> 4;
  const int base = blockIdx.x * 16;  // 3125 * 16 = 50000 exactly

  {
    float2 b = ((const float2*)bias)[lane];
    float ox, oy;
    agg_node(base + w, lane, Tb, ell, deg, b.x, b.y, ox, oy);
    *(unsigned*)(sA + w * PAD + lane * 2) =
        (unsigned)f2bf(ox) | ((unsigned)f2bf(oy) << 16);   // stride-1 uint: free
  }
  __syncthreads();

  f32x4 acc = (f32x4)(0.f);
  if (w < 8) {                       // wave w owns col-tile w (cols w*16..+16)
    const int ncol = w * 16 + l15;
#pragma unroll
    for (int ks = 0; ks < 4; ++ks) {
      const int koff = ks * 32 + quad * 8;
      bf16x8 a = *(const bf16x8*)(sA + l15 * PAD + koff);
      bf16x8 bfr;
      const float* wp = W + (size_t)koff * HID + ncol;
#pragma unroll
      for (int j = 0; j < 8; ++j) bfr[j] = (short)f2bf(wp[(size_t)j * HID]);
      acc = __builtin_amdgcn_mfma_f32_16x16x32_bf16(a, bfr, acc, 0, 0, 0);
    }
  }
  __syncthreads();                   // uniform barrier (no sync inside the if)
  if (w < 8) {
#pragma unroll
    for (int r = 0; r < 4; ++r)
      sA[(quad * 4 + r) * PAD + w * 16 + l15] = f2bf(acc[r]);
  }
  __syncthreads();
  if (tid < 256) {                   // 16 rows x 16 us8 chunks = 256
    int nrow = tid >> 4;
    int col = (tid & 15) * 8;
    *(us8*)(T2 + (size_t)(base + nrow) * HID + col) = *(const us8*)(sA + nrow * PAD + col);
  }
}

// ---------------- agg2: aggregation + bias + relu -> bf16 H (for pooling) ---
__global__ __launch_bounds__(256) void aggregate_kernel(
    const unsigned int* __restrict__ Tb, const unsigned short* __restrict__ ell,
    const int* __restrict__ deg, const float* __restrict__ bias,
    unsigned int* __restrict__ Hb) {
  int node = (blockIdx.x * blockDim.x + threadIdx.x) >> 6;
  int lane = threadIdx.x & 63;
  if (node >= N_NODES) return;
  float2 b = ((const float2*)bias)[lane];
  float ox, oy;
  agg_node(node, lane, Tb, ell, deg, b.x, b.y, ox, oy);
  Hb[(size_t)node * 64 + lane] =
      (unsigned)f2bf(ox) | ((unsigned)f2bf(oy) << 16);
}

// ---------------- pool partial sums: 4 blocks per graph -> fp32 atomics -----
__global__ __launch_bounds__(256) void pool_partial_kernel(
    const unsigned int* __restrict__ Hb, const int* __restrict__ start,
    float* __restrict__ pooled) {
  __shared__ float2 red[4][64];
  int g = blockIdx.x >> 2;
  int chunk = blockIdx.x & 3;
  int n0 = start[g], n1 = start[g + 1];
  int lane = threadIdx.x & 63, w = threadIdx.x >> 6;
  float ax = 0.f, ay = 0.f;
  for (int n = n0 + chunk * 4 + w; n < n1; n += 16) {
    unsigned h = Hb[(size_t)n * 64 + lane];
    ax += __int_as_float(h << 16);
    ay += __int_as_float(h & 0xffff0000u);
  }
  red[w][lane] = make_float2(ax, ay);
  __syncthreads();
  if (threadIdx.x < 64) {
    float2 a = red[0][lane], b = red[1][lane], c = red[2][lane], d = red[3][lane];
    atomicAdd(&pooled[g * HID + lane * 2],     a.x + b.x + c.x + d.x);
    atomicAdd(&pooled[g * HID + lane * 2 + 1], a.y + b.y + c.y + d.y);
  }
}

// ---------------- FC head + log_softmax on pooled sums (1 wave / graph) -----
__global__ __launch_bounds__(64) void head_kernel(
    const float* __restrict__ pooled, const int* __restrict__ start,
    const float* __restrict__ Wfc, const float* __restrict__ bfc,
    float* __restrict__ out) {
  int g = blockIdx.x;
  int lane = threadIdx.x;
  int o = lane & 15;
  float inv = 1.0f / fmaxf((float)(start[g + 1] - start[g]), 1.0f);
  float part = 0.f;
  for (int k = (lane >> 4); k < HID; k += 4)
    part += pooled[g * HID + k] * inv * Wfc[k * OUT_C + o];
  part += __shfl_xor(part, 16);
  part += __shfl_xor(part, 32);
  float logit = part + bfc[o];
  float m = logit;
#pragma unroll
  for (int d = 8; d >= 1; d >>= 1) m = fmaxf(m, __shfl_xor(m, d, 16));
  float e = __expf(logit - m);
  float s = e;
#pragma unroll
  for (int d = 8; d >= 1; d >>= 1) s += __shfl_xor(s, d, 16);
  float r = logit - m - __logf(s);
  if (lane < 16) out[g * OUT_C + o] = r;
}

extern "C" void kernel_launch(void* const* d_in, const int* in_sizes, int n_in,
                              void* d_out, int out_size, void* d_ws, size_t ws_size,
                              hipStream_t stream) {
  const float* x    = (const float*)d_in[0];
  const int*   ei   = (const int*)d_in[1];
  const int*   batch= (const int*)d_in[2];
  const float* W1   = (const float*)d_in[3];
  const float* b1   = (const float*)d_in[4];
  const float* W2   = (const float*)d_in[5];
  const float* b2   = (const float*)d_in[6];
  const float* Wfc  = (const float*)d_in[7];
  const float* bfc  = (const float*)d_in[8];
  float* out = (float*)d_out;
  const int* src = ei;              // edge_index[0]
  const int* dst = ei + N_EDGES;    // edge_index[1]

  char* p = (char*)d_ws;
  auto alloc = [&](size_t bytes) { char* r = p; p += (bytes + 255) & ~255ull; return r; };
  int*   degI   = (int*)alloc((size_t)N_NODES * 4);
  int*   start  = (int*)alloc((N_GRAPHS + 1) * 4);
  float* pooled = (float*)alloc((size_t)N_GRAPHS * HID * 4);
  unsigned short* ell = (unsigned short*)alloc((size_t)N_NODES * MAXDEG * 2); // 6.4 MB
  unsigned short* T   = (unsigned short*)alloc((size_t)N_NODES * HID * 2);    // 12.8 MB
  unsigned short* T2  = (unsigned short*)alloc((size_t)N_NODES * HID * 2);    // 12.8 MB
  unsigned short* Hb  = (unsigned short*)alloc((size_t)N_NODES * HID * 2);    // 12.8 MB

  hipMemsetAsync(degI, 0, (size_t)N_NODES * 4, stream);
  hipMemsetAsync(pooled, 0, (size_t)N_GRAPHS * HID * 4, stream);

  int agg_blocks = (N_NODES * 64 + 255) / 256;

  mega_kernel<<<FILLB + 1 + GEMMB, 256, 0, stream>>>(src, dst, degI, ell,
                                                     batch, start, x, W1, T);
  agg_gemm_kernel<<<AGB, 1024, 0, stream>>>((const unsigned int*)T, ell, degI,
                                            b1, W2, T2);
  aggregate_kernel<<<agg_blocks, 256, 0, stream>>>((const unsigned int*)T2, ell, degI, b2,
                                                   (unsigned int*)Hb);
  pool_partial_kernel<<<N_GRAPHS * 4, 256, 0, stream>>>((const unsigned int*)Hb, start,
                                                        pooled);
  head_kernel<<<N_GRAPHS, 64, 0, stream>>>(pooled, start, Wfc, bfc, out);
}

// Round 16
// 231.098 us; speedup vs baseline: 1.2972x; 1.0369x over previous
//
#include <hip/hip_runtime.h>

#define N_NODES  50000
#define N_EDGES  800000
#define HID      128
#define OUT_C    16
#define N_GRAPHS 128
#define MAXDEG   64     // Poisson(16): P(deg>=64) ~ 1e-19/node — clamped anyway
#define NSLICE   6250   // N_NODES / 8; slice s owns [s*6250,(s+1)*6250)
#define EPB      2048   // edges per fill chunk (r16: halved again — r15 trend)
#define FILLB    3128   // 391 chunks x 8 slices
#define GEMMB    782    // ceil(50000/64)
#define AGB      3125   // 50000 / 16 exactly
#define PAD      136    // +8 bf16 pad -> frag reads 2-way (free) not 16-way

typedef __attribute__((ext_vector_type(8))) short bf16x8;
typedef __attribute__((ext_vector_type(4))) float f32x4;
typedef __attribute__((ext_vector_type(8))) unsigned short us8;
typedef __attribute__((ext_vector_type(4))) unsigned short us4;

__device__ __forceinline__ unsigned short f2bf(float f) {
  unsigned u = __float_as_uint(f);
  u += 0x7fffu + ((u >> 16) & 1u);   // RNE
  return (unsigned short)(u >> 16);
}

// ---------------- shared MFMA compute+store, 256-thread version -------------
// 16x16x32 MFMA; A: m=lane&15,k=quad*8+j (LDS); B: n=lane&15,k=quad*8+j
// loaded straight from global fp32 W[k][n] (L2-broadcast, no LDS, no
// transpose-conflicts). C/D: col=lane&15,row=quad*4+reg.
__device__ __forceinline__ void gemm_compute_store(
    unsigned short* sA, const float* __restrict__ W,
    unsigned short* __restrict__ T, int base) {
  const int tid = threadIdx.x;
  const int lane = tid & 63;
  const int w = tid >> 6;
  const int l15 = lane & 15;
  const int quad = lane >> 4;
  __syncthreads();

  f32x4 acc[4][2];
#pragma unroll
  for (int nt = 0; nt < 4; ++nt)
#pragma unroll
    for (int c = 0; c < 2; ++c) acc[nt][c] = (f32x4)(0.f);

  const int ct0 = w * 2;
  const int ncol = ct0 * 16 + l15;
#pragma unroll
  for (int ks = 0; ks < 4; ++ks) {
    const int koff = ks * 32 + quad * 8;
    bf16x8 a[4], bfr[2];
#pragma unroll
    for (int c = 0; c < 2; ++c) {
      const float* wp = W + (size_t)koff * HID + ncol + c * 16;
#pragma unroll
      for (int j = 0; j < 8; ++j) bfr[c][j] = (short)f2bf(wp[(size_t)j * HID]);
    }
#pragma unroll
    for (int nt = 0; nt < 4; ++nt)
      a[nt] = *(const bf16x8*)(sA + (nt * 16 + l15) * PAD + koff);
#pragma unroll
    for (int nt = 0; nt < 4; ++nt)
#pragma unroll
      for (int c = 0; c < 2; ++c)
        acc[nt][c] = __builtin_amdgcn_mfma_f32_16x16x32_bf16(a[nt], bfr[c], acc[nt][c], 0, 0, 0);
  }
  __syncthreads();

#pragma unroll
  for (int nt = 0; nt < 4; ++nt)
#pragma unroll
    for (int c = 0; c < 2; ++c)
#pragma unroll
      for (int r = 0; r < 4; ++r)
        sA[(nt * 16 + quad * 4 + r) * PAD + (ct0 + c) * 16 + l15] = f2bf(acc[nt][c][r]);
  __syncthreads();
#pragma unroll
  for (int i = 0; i < 4; ++i) {
    int idx = tid + i * 256;
    int nrow = idx >> 4;
    int col = (idx & 15) * 8;
    int node = base + nrow;
    if (node < N_NODES)
      *(us8*)(T + (size_t)node * HID + col) = *(const us8*)(sA + nrow * PAD + col);
  }
}

// stage A from fp32 (convert to bf16): 64 rows x 32 float4 = 2048
__device__ __forceinline__ void stage_a_f32(unsigned short* sA,
                                            const float* __restrict__ H, int base) {
#pragma unroll
  for (int i = 0; i < 8; ++i) {
    int idx = threadIdx.x + i * 256;
    int nrow = idx >> 5;
    int c4 = (idx & 31) * 4;
    float4 v = make_float4(0.f, 0.f, 0.f, 0.f);
    int node = base + nrow;
    if (node < N_NODES) v = *(const float4*)(H + (size_t)node * HID + c4);
    us4 b;
    b.x = f2bf(v.x); b.y = f2bf(v.y); b.z = f2bf(v.z); b.w = f2bf(v.w);
    *(us4*)(sA + nrow * PAD + c4) = b;
  }
}

// ---- mega: fill (0..3127) | bounds (3128) | gemm1 (3129..3910) -------------
// fill scatter latency is partially hideable with more waves (r15: EPB
// 8192->4096 took mega 67.5->63); r16 probes 2048. gemm1 hides under fill.
__global__ __launch_bounds__(256) void mega_kernel(
    const int* __restrict__ src, const int* __restrict__ dst,
    int* __restrict__ deg, unsigned short* __restrict__ ell,
    const int* __restrict__ batch, int* __restrict__ start,
    const float* __restrict__ x, const float* __restrict__ W1,
    unsigned short* __restrict__ T) {
  __shared__ unsigned short sA[64 * PAD];   // 17.4 KB
  int b = blockIdx.x;
  if (b < FILLB) {
    const int slice = b & 7;
    const int e0 = (b >> 3) * EPB;
    const int e1 = min(e0 + EPB, N_EDGES);
    const unsigned lo = slice * NSLICE;
    for (int e = e0 + threadIdx.x; e < e1; e += 256) {
      int d = __builtin_nontemporal_load(dst + e);
      if ((unsigned)(d - lo) < (unsigned)NSLICE) {
        int p = atomicAdd(&deg[d], 1);
        if (p < MAXDEG) ell[(d << 6) + p] = (unsigned short)src[e];
      }
    }
  } else if (b == FILLB) {
    int t = threadIdx.x;                       // graph bounds (batch sorted)
    if (t <= N_GRAPHS) {
      int lo = 0, hi = N_NODES;
      while (lo < hi) {
        int mid = (lo + hi) >> 1;
        if (batch[mid] < t) lo = mid + 1; else hi = mid;
      }
      start[t] = lo;
    }
  } else {
    const int base = (b - FILLB - 1) * 64;
    stage_a_f32(sA, x, base);
    gemm_compute_store(sA, W1, T, base);
  }
}

// ------- agg core, pass 1: gathers deg[src] (scattered, once) + PACKS -------
// lane owns 2 bf16 channels; coalesced ell load + scattered deg gather, then
// readlane-broadcast with 8 independent row gathers in flight (r12-measured
// optimum). Packs (src | fp16(weight)<<16) into ellw so pass 2 never touches
// deg[] and does 1 readlane/edge instead of 2.
__device__ __forceinline__ void agg_node_pack(
    int node, int lane, const unsigned int* __restrict__ Tb,
    const unsigned short* __restrict__ ell, const int* __restrict__ deg,
    unsigned int* __restrict__ ellw,
    float bx, float by, float& ox, float& oy) {
  int dn = deg[node];
  float dd = rsqrtf((float)dn + 1.0f);
  unsigned sv = Tb[(size_t)node * 64 + lane];
  float wself = dd * dd;
  float ax = __int_as_float(sv << 16) * wself;
  float ay = __int_as_float(sv & 0xffff0000u) * wself;
  int m = min(dn, MAXDEG);
  int s0 = node << 6;
  int sidx = 0; float wv = 0.f;
  if (lane < m) {
    sidx = (int)ell[s0 + lane];       // coalesced (ELL row contiguous)
    wv = rsqrtf((float)deg[sidx] + 1.0f) * dd;   // scattered gather (only here)
    unsigned short hw = __builtin_bit_cast(unsigned short, (_Float16)wv);
    ellw[s0 + lane] = (unsigned)sidx | ((unsigned)hw << 16);
  }
  int j = 0;
  for (; j + 8 <= m; j += 8) {
#pragma unroll
    for (int q = 0; q < 8; ++q) {     // 8 independent row gathers in flight
      int s = __builtin_amdgcn_readlane(sidx, j + q);
      float w = __int_as_float(__builtin_amdgcn_readlane(__float_as_int(wv), j + q));
      unsigned t = Tb[(size_t)s * 64 + lane];
      ax += w * __int_as_float(t << 16);
      ay += w * __int_as_float(t & 0xffff0000u);
    }
  }
  for (; j < m; ++j) {
    int s = __builtin_amdgcn_readlane(sidx, j);
    float w = __int_as_float(__builtin_amdgcn_readlane(__float_as_int(wv), j));
    unsigned t = Tb[(size_t)s * 64 + lane];
    ax += w * __int_as_float(t << 16);
    ay += w * __int_as_float(t & 0xffff0000u);
  }
  ox = fmaxf(ax + bx, 0.f);
  oy = fmaxf(ay + by, 0.f);
}

// ------- agg core, pass 2: consumes packed (src|fp16 w) — no deg gather -----
__device__ __forceinline__ void agg_node_packed(
    int node, int lane, const unsigned int* __restrict__ Tb,
    const unsigned int* __restrict__ ellw, const int* __restrict__ deg,
    float bx, float by, float& ox, float& oy) {
  int dn = deg[node];
  float dd = rsqrtf((float)dn + 1.0f);
  unsigned sv = Tb[(size_t)node * 64 + lane];
  float wself = dd * dd;
  float ax = __int_as_float(sv << 16) * wself;
  float ay = __int_as_float(sv & 0xffff0000u) * wself;
  int m = min(dn, MAXDEG);
  unsigned pw = 0;
  if (lane < m) pw = ellw[(node << 6) + lane];   // coalesced
  int j = 0;
  for (; j + 8 <= m; j += 8) {
#pragma unroll
    for (int q = 0; q < 8; ++q) {     // 8 independent row gathers in flight
      unsigned v = (unsigned)__builtin_amdgcn_readlane((int)pw, j + q);
      int s = (int)(v & 0xffffu);
      float w = (float)__builtin_bit_cast(_Float16, (unsigned short)(v >> 16));
      unsigned t = Tb[(size_t)s * 64 + lane];
      ax += w * __int_as_float(t << 16);
      ay += w * __int_as_float(t & 0xffff0000u);
    }
  }
  for (; j < m; ++j) {
    unsigned v = (unsigned)__builtin_amdgcn_readlane((int)pw, j);
    int s = (int)(v & 0xffffu);
    float w = (float)__builtin_bit_cast(_Float16, (unsigned short)(v >> 16));
    unsigned t = Tb[(size_t)s * 64 + lane];
    ax += w * __int_as_float(t << 16);
    ay += w * __int_as_float(t & 0xffff0000u);
  }
  ox = fmaxf(ax + bx, 0.f);
  oy = fmaxf(ay + by, 0.f);
}

// ---------------- fused agg1 + gemm2, one node per wave ---------------------
// 3125 blocks x 16 waves = 50000 waves (full agg TLP), 16-row MFMA tile on
// W2 (8 active waves, 1 col-tile each, B direct from global fp32).
__global__ __launch_bounds__(1024) void agg_gemm_kernel(
    const unsigned int* __restrict__ Tb, const unsigned short* __restrict__ ell,
    const int* __restrict__ deg, const float* __restrict__ bias,
    const float* __restrict__ W, unsigned int* __restrict__ ellw,
    unsigned short* __restrict__ T2) {
  __shared__ unsigned short sA[16 * PAD];   // 4.4 KB
  const int tid = threadIdx.x;
  const int lane = tid & 63;
  const int w = tid >> 6;            // 0..15 — one node per wave
  const int l15 = lane & 15;
  const int quad = lane >> 4;
  const int base = blockIdx.x * 16;  // 3125 * 16 = 50000 exactly

  {
    float2 b = ((const float2*)bias)[lane];
    float ox, oy;
    agg_node_pack(base + w, lane, Tb, ell, deg, ellw, b.x, b.y, ox, oy);
    *(unsigned*)(sA + w * PAD + lane * 2) =
        (unsigned)f2bf(ox) | ((unsigned)f2bf(oy) << 16);   // stride-1 uint: free
  }
  __syncthreads();

  f32x4 acc = (f32x4)(0.f);
  if (w < 8) {                       // wave w owns col-tile w (cols w*16..+16)
    const int ncol = w * 16 + l15;
#pragma unroll
    for (int ks = 0; ks < 4; ++ks) {
      const int koff = ks * 32 + quad * 8;
      bf16x8 a = *(const bf16x8*)(sA + l15 * PAD + koff);
      bf16x8 bfr;
      const float* wp = W + (size_t)koff * HID + ncol;
#pragma unroll
      for (int j = 0; j < 8; ++j) bfr[j] = (short)f2bf(wp[(size_t)j * HID]);
      acc = __builtin_amdgcn_mfma_f32_16x16x32_bf16(a, bfr, acc, 0, 0, 0);
    }
  }
  __syncthreads();                   // uniform barrier (no sync inside the if)
  if (w < 8) {
#pragma unroll
    for (int r = 0; r < 4; ++r)
      sA[(quad * 4 + r) * PAD + w * 16 + l15] = f2bf(acc[r]);
  }
  __syncthreads();
  if (tid < 256) {                   // 16 rows x 16 us8 chunks = 256
    int nrow = tid >> 4;
    int col = (tid & 15) * 8;
    *(us8*)(T2 + (size_t)(base + nrow) * HID + col) = *(const us8*)(sA + nrow * PAD + col);
  }
}

// ---------------- agg2: packed-weight aggregation -> bf16 H -----------------
__global__ __launch_bounds__(256) void aggregate_kernel(
    const unsigned int* __restrict__ Tb, const unsigned int* __restrict__ ellw,
    const int* __restrict__ deg, const float* __restrict__ bias,
    unsigned int* __restrict__ Hb) {
  int node = (blockIdx.x * blockDim.x + threadIdx.x) >> 6;
  int lane = threadIdx.x & 63;
  if (node >= N_NODES) return;
  float2 b = ((const float2*)bias)[lane];
  float ox, oy;
  agg_node_packed(node, lane, Tb, ellw, deg, b.x, b.y, ox, oy);
  Hb[(size_t)node * 64 + lane] =
      (unsigned)f2bf(ox) | ((unsigned)f2bf(oy) << 16);
}

// ---------------- pool partial sums: 4 blocks per graph -> fp32 atomics -----
__global__ __launch_bounds__(256) void pool_partial_kernel(
    const unsigned int* __restrict__ Hb, const int* __restrict__ start,
    float* __restrict__ pooled) {
  __shared__ float2 red[4][64];
  int g = blockIdx.x >> 2;
  int chunk = blockIdx.x & 3;
  int n0 = start[g], n1 = start[g + 1];
  int lane = threadIdx.x & 63, w = threadIdx.x >> 6;
  float ax = 0.f, ay = 0.f;
  for (int n = n0 + chunk * 4 + w; n < n1; n += 16) {
    unsigned h = Hb[(size_t)n * 64 + lane];
    ax += __int_as_float(h << 16);
    ay += __int_as_float(h & 0xffff0000u);
  }
  red[w][lane] = make_float2(ax, ay);
  __syncthreads();
  if (threadIdx.x < 64) {
    float2 a = red[0][lane], b = red[1][lane], c = red[2][lane], d = red[3][lane];
    atomicAdd(&pooled[g * HID + lane * 2],     a.x + b.x + c.x + d.x);
    atomicAdd(&pooled[g * HID + lane * 2 + 1], a.y + b.y + c.y + d.y);
  }
}

// ---------------- FC head + log_softmax on pooled sums (1 wave / graph) -----
__global__ __launch_bounds__(64) void head_kernel(
    const float* __restrict__ pooled, const int* __restrict__ start,
    const float* __restrict__ Wfc, const float* __restrict__ bfc,
    float* __restrict__ out) {
  int g = blockIdx.x;
  int lane = threadIdx.x;
  int o = lane & 15;
  float inv = 1.0f / fmaxf((float)(start[g + 1] - start[g]), 1.0f);
  float part = 0.f;
  for (int k = (lane >> 4); k < HID; k += 4)
    part += pooled[g * HID + k] * inv * Wfc[k * OUT_C + o];
  part += __shfl_xor(part, 16);
  part += __shfl_xor(part, 32);
  float logit = part + bfc[o];
  float m = logit;
#pragma unroll
  for (int d = 8; d >= 1; d >>= 1) m = fmaxf(m, __shfl_xor(m, d, 16));
  float e = __expf(logit - m);
  float s = e;
#pragma unroll
  for (int d = 8; d >= 1; d >>= 1) s += __shfl_xor(s, d, 16);
  float r = logit - m - __logf(s);
  if (lane < 16) out[g * OUT_C + o] = r;
}

extern "C" void kernel_launch(void* const* d_in, const int* in_sizes, int n_in,
                              void* d_out, int out_size, void* d_ws, size_t ws_size,
                              hipStream_t stream) {
  const float* x    = (const float*)d_in[0];
  const int*   ei   = (const int*)d_in[1];
  const int*   batch= (const int*)d_in[2];
  const float* W1   = (const float*)d_in[3];
  const float* b1   = (const float*)d_in[4];
  const float* W2   = (const float*)d_in[5];
  const float* b2   = (const float*)d_in[6];
  const float* Wfc  = (const float*)d_in[7];
  const float* bfc  = (const float*)d_in[8];
  float* out = (float*)d_out;
  const int* src = ei;              // edge_index[0]
  const int* dst = ei + N_EDGES;    // edge_index[1]

  char* p = (char*)d_ws;
  auto alloc = [&](size_t bytes) { char* r = p; p += (bytes + 255) & ~255ull; return r; };
  // degI and pooled adjacent -> a single memset covers both
  int*   degI   = (int*)alloc((size_t)N_NODES * 4);                           // 200192 B padded
  float* pooled = (float*)alloc((size_t)N_GRAPHS * HID * 4);                  // 65536 B
  int*   start  = (int*)alloc((N_GRAPHS + 1) * 4);
  unsigned short* ell = (unsigned short*)alloc((size_t)N_NODES * MAXDEG * 2); // 6.4 MB
  unsigned int*   ellw= (unsigned int*)alloc((size_t)N_NODES * MAXDEG * 4);   // 12.8 MB
  unsigned short* T   = (unsigned short*)alloc((size_t)N_NODES * HID * 2);    // 12.8 MB
  unsigned short* T2  = (unsigned short*)alloc((size_t)N_NODES * HID * 2);    // 12.8 MB
  unsigned short* Hb  = (unsigned short*)alloc((size_t)N_NODES * HID * 2);    // 12.8 MB

  hipMemsetAsync(degI, 0, ((size_t)N_NODES * 4 + 255 & ~255ull) +
                          (size_t)N_GRAPHS * HID * 4, stream);

  int agg_blocks = (N_NODES * 64 + 255) / 256;

  mega_kernel<<<FILLB + 1 + GEMMB, 256, 0, stream>>>(src, dst, degI, ell,
                                                     batch, start, x, W1, T);
  agg_gemm_kernel<<<AGB, 1024, 0, stream>>>((const unsigned int*)T, ell, degI,
                                            b1, W2, ellw, T2);
  aggregate_kernel<<<agg_blocks, 256, 0, stream>>>((const unsigned int*)T2, ellw, degI, b2,
                                                   (unsigned int*)Hb);
  pool_partial_kernel<<<N_GRAPHS * 4, 256, 0, stream>>>((const unsigned int*)Hb, start,
                                                        pooled);
  head_kernel<<<N_GRAPHS, 64, 0, stream>>>(pooled, start, Wfc, bfc, out);
}